// Round 1
// baseline (624.938 us; speedup 1.0000x reference)
//
#include <hip/hip_runtime.h>

// Problem constants (from reference setup_inputs): B=4, h=w=z=16, C=128, Cq=16
#define NB   4
#define NN   4096      // h*w*z
#define NC   128
#define NCQ  16
#define NROWS (NB * NN)  // 16384

// ---------------------------------------------------------------------------
// Kernel 1: fused 1x1x1 conv projections.
//   X [16384,128] fp32 row-major  ->  b [16384,16], c [16384,16], d [16384,128]
// Block = 256 threads handles 32 rows; W staged per 32-col chunk in LDS.
// ---------------------------------------------------------------------------
__global__ __launch_bounds__(256) void proj_kernel(
    const float* __restrict__ x,  const float* __restrict__ Wb,
    const float* __restrict__ Wc, const float* __restrict__ Wd,
    float* __restrict__ bq, float* __restrict__ cq, float* __restrict__ dv)
{
    __shared__ float xs[32][128];    // 16 KB x tile
    __shared__ float wsh[128][32];   // 16 KB W chunk

    const int  t    = threadIdx.x;
    const long row0 = (long)blockIdx.x * 32;

    {   // stage x tile: 4096 floats = 1024 float4, coalesced
        const float4* xg  = (const float4*)(x + row0 * NC);
        float4*       xs4 = (float4*)&xs[0][0];
        for (int i = t; i < 32 * NC / 4; i += 256) xs4[i] = xg[i];
    }

    const int col = t & 31;
    const int rg  = t >> 5;   // 0..7

    for (int chunk = 0; chunk < 5; ++chunk) {
        __syncthreads();
        // stage W chunk [128][32]: chunk 0 = [Wb | Wc], chunks 1..4 = Wd cols
        for (int i = t; i < 128 * 32; i += 256) {
            int k = i >> 5, c2 = i & 31;
            float w;
            if (chunk == 0) w = (c2 < 16) ? Wb[k * 16 + c2] : Wc[k * 16 + (c2 - 16)];
            else            w = Wd[k * 128 + (chunk - 1) * 32 + c2];
            wsh[k][c2] = w;
        }
        __syncthreads();

        float acc0 = 0.f, acc1 = 0.f, acc2 = 0.f, acc3 = 0.f;
        #pragma unroll 8
        for (int k = 0; k < 128; k += 4) {
            float w0 = wsh[k][col],   w1 = wsh[k+1][col];
            float w2 = wsh[k+2][col], w3 = wsh[k+3][col];
            float4 x0 = *(const float4*)&xs[rg     ][k];
            float4 x1 = *(const float4*)&xs[rg +  8][k];
            float4 x2 = *(const float4*)&xs[rg + 16][k];
            float4 x3 = *(const float4*)&xs[rg + 24][k];
            acc0 += x0.x*w0 + x0.y*w1 + x0.z*w2 + x0.w*w3;
            acc1 += x1.x*w0 + x1.y*w1 + x1.z*w2 + x1.w*w3;
            acc2 += x2.x*w0 + x2.y*w1 + x2.z*w2 + x2.w*w3;
            acc3 += x3.x*w0 + x3.y*w1 + x3.z*w2 + x3.w*w3;
        }
        float accs[4] = {acc0, acc1, acc2, acc3};
        #pragma unroll
        for (int rr = 0; rr < 4; ++rr) {
            long row = row0 + rg + 8 * rr;
            if (chunk == 0) {
                if (col < 16) bq[row * NCQ + col]        = accs[rr];
                else          cq[row * NCQ + (col - 16)] = accs[rr];
            } else {
                dv[row * NC + (chunk - 1) * 32 + col] = accs[rr];
            }
        }
    }
}

// ---------------------------------------------------------------------------
// Kernel 2: fused flash attention + epilogue (gamma*attn_out + x).
// Grid = 256 blocks (4 batches x 64 row-tiles), 256 threads = 4 waves.
// Block owns 64 Q rows. Thread t owns rows rA=t>>3, rB=rA+32 and channels
// c = (t&7)*4 + 32*j (j=0..3)  -> V-tile b128 LDS reads are bank-conflict-free.
// Online softmax state (m,l) per row replicated across the row's 8 lanes.
// ---------------------------------------------------------------------------
__global__ __launch_bounds__(256) void attn_kernel(
    const float* __restrict__ bq, const float* __restrict__ cq,
    const float* __restrict__ dv, const float* __restrict__ x,
    const float* __restrict__ gamma, float* __restrict__ out)
{
    __shared__ float ks[64][20];      // K tile, padded stride 20 (5 KB)
    __shared__ float vs[64 * 128];    // V tile (32 KB)
    __shared__ float ps[64][65];      // P tile, stride 65 => conflict-free (16.25 KB)

    const int  t     = threadIdx.x;
    const int  batch = blockIdx.x >> 6;
    const int  tile  = blockIdx.x & 63;
    const long base  = (long)batch * NN;
    const int  r0    = tile * 64;
    const int  g     = t & 7;
    const int  rA    = t >> 3;       // 0..31
    const int  rB    = rA + 32;

    // q rows -> registers (broadcast reads, L1-served)
    float qa[16], qb[16];
    {
        const float4* qga = (const float4*)(bq + (base + r0 + rA) * NCQ);
        const float4* qgb = (const float4*)(bq + (base + r0 + rB) * NCQ);
        #pragma unroll
        for (int i = 0; i < 4; ++i) {
            float4 va = qga[i], vb = qgb[i];
            qa[4*i+0]=va.x; qa[4*i+1]=va.y; qa[4*i+2]=va.z; qa[4*i+3]=va.w;
            qb[4*i+0]=vb.x; qb[4*i+1]=vb.y; qb[4*i+2]=vb.z; qb[4*i+3]=vb.w;
        }
    }

    float mA = -1e30f, lA = 0.f, mB = -1e30f, lB = 0.f;
    float oA[16], oB[16];
    #pragma unroll
    for (int i = 0; i < 16; ++i) { oA[i] = 0.f; oB[i] = 0.f; }

    for (int m0 = 0; m0 < NN; m0 += 64) {
        __syncthreads();   // prev accumulate done before restaging ks/vs
        {   // stage K tile into padded layout (256 float4)
            const float4* kg = (const float4*)(cq + (base + m0) * NCQ);
            float4 v = kg[t];
            *(float4*)&ks[t >> 2][(t & 3) * 4] = v;
            // stage V tile (2048 float4)
            const float4* vg  = (const float4*)(dv + (base + m0) * NC);
            float4*       vs4 = (float4*)vs;
            #pragma unroll
            for (int i = 0; i < 8; ++i) vs4[t + 256 * i] = vg[t + 256 * i];
        }
        __syncthreads();

        // ---- scores for rows rA,rB at m = g + 8*jj (bank-interleaved) ----
        float sA[8], sB[8];
        float tmaxA = -1e30f, tmaxB = -1e30f;
        #pragma unroll
        for (int jj = 0; jj < 8; ++jj) {
            int m = g + 8 * jj;
            float a = 0.f, b = 0.f;
            #pragma unroll
            for (int i = 0; i < 16; i += 4) {
                float4 kv = *(const float4*)&ks[m][i];
                a += qa[i]*kv.x + qa[i+1]*kv.y + qa[i+2]*kv.z + qa[i+3]*kv.w;
                b += qb[i]*kv.x + qb[i+1]*kv.y + qb[i+2]*kv.z + qb[i+3]*kv.w;
            }
            sA[jj] = a; sB[jj] = b;
            tmaxA = fmaxf(tmaxA, a); tmaxB = fmaxf(tmaxB, b);
        }
        // tile max across the row's 8 lanes (consecutive lanes, same wave)
        #pragma unroll
        for (int off = 1; off < 8; off <<= 1) {
            tmaxA = fmaxf(tmaxA, __shfl_xor(tmaxA, off, 64));
            tmaxB = fmaxf(tmaxB, __shfl_xor(tmaxB, off, 64));
        }
        float nmA = fmaxf(mA, tmaxA), nmB = fmaxf(mB, tmaxB);
        float alA = __expf(mA - nmA), alB = __expf(mB - nmB);
        float tsA = 0.f, tsB = 0.f;
        #pragma unroll
        for (int jj = 0; jj < 8; ++jj) {
            float pa = __expf(sA[jj] - nmA);
            float pb = __expf(sB[jj] - nmB);
            ps[rA][g + 8*jj] = pa;
            ps[rB][g + 8*jj] = pb;
            tsA += pa; tsB += pb;
        }
        #pragma unroll
        for (int off = 1; off < 8; off <<= 1) {
            tsA += __shfl_xor(tsA, off, 64);
            tsB += __shfl_xor(tsB, off, 64);
        }
        mA = nmA; lA = lA * alA + tsA;
        mB = nmB; lB = lB * alB + tsB;
        #pragma unroll
        for (int i = 0; i < 16; ++i) { oA[i] *= alA; oB[i] *= alB; }
        __syncthreads();

        // ---- PV accumulate: o[c] += p_m * V[m][c] ----
        #pragma unroll 4
        for (int mm = 0; mm < 64; ++mm) {
            float pa = ps[rA][mm];
            float pb = ps[rB][mm];
            const float* vr = &vs[mm * NC + g * 4];
            float4 v0 = *(const float4*)(vr);
            float4 v1 = *(const float4*)(vr + 32);
            float4 v2 = *(const float4*)(vr + 64);
            float4 v3 = *(const float4*)(vr + 96);
            oA[ 0]+=pa*v0.x; oA[ 1]+=pa*v0.y; oA[ 2]+=pa*v0.z; oA[ 3]+=pa*v0.w;
            oA[ 4]+=pa*v1.x; oA[ 5]+=pa*v1.y; oA[ 6]+=pa*v1.z; oA[ 7]+=pa*v1.w;
            oA[ 8]+=pa*v2.x; oA[ 9]+=pa*v2.y; oA[10]+=pa*v2.z; oA[11]+=pa*v2.w;
            oA[12]+=pa*v3.x; oA[13]+=pa*v3.y; oA[14]+=pa*v3.z; oA[15]+=pa*v3.w;
            oB[ 0]+=pb*v0.x; oB[ 1]+=pb*v0.y; oB[ 2]+=pb*v0.z; oB[ 3]+=pb*v0.w;
            oB[ 4]+=pb*v1.x; oB[ 5]+=pb*v1.y; oB[ 6]+=pb*v1.z; oB[ 7]+=pb*v1.w;
            oB[ 8]+=pb*v2.x; oB[ 9]+=pb*v2.y; oB[10]+=pb*v2.z; oB[11]+=pb*v2.w;
            oB[12]+=pb*v3.x; oB[13]+=pb*v3.y; oB[14]+=pb*v3.z; oB[15]+=pb*v3.w;
        }
    }

    // ---- epilogue: out = gamma * (o / l) + x ----
    const float gm = gamma[0];
    const float iA = 1.f / lA, iB = 1.f / lB;
    #pragma unroll
    for (int j = 0; j < 4; ++j) {
        int  c  = g * 4 + 32 * j;
        long ia = (base + r0 + rA) * NC + c;
        long ib = (base + r0 + rB) * NC + c;
        float4 xa = *(const float4*)&x[ia];
        float4 xb = *(const float4*)&x[ib];
        float4 oa, ob;
        oa.x = gm * (oA[4*j+0] * iA) + xa.x;
        oa.y = gm * (oA[4*j+1] * iA) + xa.y;
        oa.z = gm * (oA[4*j+2] * iA) + xa.z;
        oa.w = gm * (oA[4*j+3] * iA) + xa.w;
        ob.x = gm * (oB[4*j+0] * iB) + xb.x;
        ob.y = gm * (oB[4*j+1] * iB) + xb.y;
        ob.z = gm * (oB[4*j+2] * iB) + xb.z;
        ob.w = gm * (oB[4*j+3] * iB) + xb.w;
        *(float4*)&out[ia] = oa;
        *(float4*)&out[ib] = ob;
    }
}

// ---------------------------------------------------------------------------
extern "C" void kernel_launch(void* const* d_in, const int* in_sizes, int n_in,
                              void* d_out, int out_size, void* d_ws, size_t ws_size,
                              hipStream_t stream) {
    const float* x     = (const float*)d_in[0];
    const float* Wb    = (const float*)d_in[1];
    const float* Wc    = (const float*)d_in[2];
    const float* Wd    = (const float*)d_in[3];
    const float* gamma = (const float*)d_in[4];
    float*       out   = (float*)d_out;

    // workspace layout (floats): b [16384*16] | c [16384*16] | d [16384*128]
    float* bq = (float*)d_ws;
    float* cq = bq + (long)NROWS * NCQ;
    float* dv = cq + (long)NROWS * NCQ;

    proj_kernel<<<NROWS / 32, 256, 0, stream>>>(x, Wb, Wc, Wd, bq, cq, dv);
    attn_kernel<<<NB * (NN / 64), 256, 0, stream>>>(bq, cq, dv, x, gamma, out);
}

// Round 2
// 218.573 us; speedup vs baseline: 2.8592x; 2.8592x over previous
//
#include <hip/hip_runtime.h>

// Problem constants: B=4, h=w=z=16 -> N=4096, C=128, Cq=16
#define NB    4
#define NN    4096
#define NC    128
#define NCQ   16
#define NROWS (NB * NN)   // 16384

typedef __attribute__((ext_vector_type(8))) __bf16 bf16x8;
typedef __attribute__((ext_vector_type(4))) float  f32x4;

#define MFMA16(a, b, c) __builtin_amdgcn_mfma_f32_16x16x32_bf16((a), (b), (c), 0, 0, 0)
#define LOG2E 1.44269504f

// ---------------------------------------------------------------------------
// Kernel 1: projections via MFMA.  X[64,128] per block; W = [Wb|Wc|Wd] 160 cols.
// Computes D' = W^T * X^T so BOTH fragments are contiguous row-major LDS reads:
//   A-frag = wt[outcol][ch..ch+7], B-frag = xsh[row][ch..ch+7].
// Outputs: bqh/cqh [row][16] bf16 row-major, dvt [batch][ch][4096] bf16 (V^T).
// ---------------------------------------------------------------------------
__global__ __launch_bounds__(256) void proj_kernel(
    const float* __restrict__ x,  const float* __restrict__ Wb,
    const float* __restrict__ Wc, const float* __restrict__ Wd,
    __bf16* __restrict__ bqh, __bf16* __restrict__ cqh, __bf16* __restrict__ dvt)
{
    __shared__ __align__(16) __bf16 xsh[64 * 136];   // [row][136], 17.4 KB
    __shared__ __align__(16) __bf16 wt [160 * 136];  // [outcol][136], 43.5 KB
    __shared__ __align__(16) float  osb[4][16 * 17]; // per-wave transpose buffer

    const int  t    = threadIdx.x;
    const int  lane = t & 63, w = t >> 6;
    const int  q16  = lane & 15, quad = lane >> 4;
    const long row0 = (long)blockIdx.x * 64;
    const int  batch = (int)(row0 >> 12);
    const int  nloc  = (int)(row0 & 4095);

    // ---- stage X tile (fp32 -> bf16), [64][128] -> xsh stride 136 ----
    #pragma unroll
    for (int i = 0; i < 8; ++i) {
        int idx = t + 256 * i;           // < 2048
        int r = idx >> 5, c4 = (idx & 31) * 4;
        float4 xv = *(const float4*)&x[(row0 + r) * NC + c4];
        union { __bf16 h[4]; uint2 u; } cv;
        cv.h[0] = (__bf16)xv.x; cv.h[1] = (__bf16)xv.y;
        cv.h[2] = (__bf16)xv.z; cv.h[3] = (__bf16)xv.w;
        *(uint2*)&xsh[r * 136 + c4] = cv.u;
    }
    // ---- stage W^T: wt[oc][ch], oc: 0..15 Wb, 16..31 Wc, 32..159 Wd ----
    for (int i = 0; i < 80; ++i) {
        int idx = t + 256 * i;           // < 20480
        int oc = idx % 160, ch = idx / 160;
        float v;
        if      (oc < 16) v = Wb[ch * 16 + oc];
        else if (oc < 32) v = Wc[ch * 16 + (oc - 16)];
        else              v = Wd[ch * 128 + (oc - 32)];
        wt[oc * 136 + ch] = (__bf16)v;
    }
    __syncthreads();

    // B-frags (X^T): n = x-row = w*16 + q16, k = ch
    bf16x8 xf[4];
    #pragma unroll
    for (int kc = 0; kc < 4; ++kc)
        xf[kc] = *(const bf16x8*)&xsh[(w * 16 + q16) * 136 + kc * 32 + quad * 8];

    float* osw = osb[w];
    for (int oct = 0; oct < 10; ++oct) {
        f32x4 acc = {0.f, 0.f, 0.f, 0.f};
        #pragma unroll
        for (int kc = 0; kc < 4; ++kc) {
            bf16x8 wf = *(const bf16x8*)&wt[(oct * 16 + q16) * 136 + kc * 32 + quad * 8];
            acc = MFMA16(wf, xf[kc], acc);   // D'[oc][row]
        }
        // D' layout: col = x-row = lane&15, row = oc16 = quad*4+reg
        #pragma unroll
        for (int r = 0; r < 4; ++r)
            osw[(quad * 4 + r) * 17 + q16] = acc[r];   // osb[oc16][xrow]

        if (oct >= 2) {   // -> dvt[ch][row], pack 4 consecutive rows
            int ocp = lane >> 2, rseg = (lane & 3) * 4;
            union { __bf16 h[4]; uint2 u; } cv;
            #pragma unroll
            for (int j = 0; j < 4; ++j) cv.h[j] = (__bf16)osw[ocp * 17 + rseg + j];
            int ch = (oct - 2) * 16 + ocp;
            size_t g = ((size_t)batch * 128 + ch) * 4096 + nloc + w * 16 + rseg;
            *(uint2*)&dvt[g] = cv.u;
        } else {          // -> bqh/cqh row-major
            int r = lane >> 2, seg = lane & 3;
            union { __bf16 h[4]; uint2 u; } cv;
            #pragma unroll
            for (int j = 0; j < 4; ++j) cv.h[j] = (__bf16)osw[(seg * 4 + j) * 17 + r];
            __bf16* dst = (oct == 0) ? bqh : cqh;
            size_t g = (size_t)(row0 + w * 16 + r) * NCQ + seg * 4;
            *(uint2*)&dst[g] = cv.u;
        }
    }
}

// ---------------------------------------------------------------------------
// Kernel 2: flash attention via MFMA + epilogue.
// Grid 256 = 4 batches x 64 Q-tiles of 64 rows; 4 waves, wave owns 16 Q rows.
// Per 64-key tile: S = Q*K^T (4 MFMA, k padded to 32 with zeros), online
// softmax, P -> LDS [q][key], O^T = V^T * P^T (16 MFMA). LDS-transposed
// coalesced epilogue: out = gamma*(O/l) + x.
// ---------------------------------------------------------------------------
__global__ __launch_bounds__(256) void attn_kernel(
    const __bf16* __restrict__ bqh, const __bf16* __restrict__ cqh,
    const __bf16* __restrict__ dvt, const float* __restrict__ x,
    const float* __restrict__ gamma, float* __restrict__ out)
{
    __shared__ __align__(16) __bf16 vt[128 * 72];   // V^T tile [ch][72], 18.4 KB
    __shared__ __align__(16) __bf16 ks[64 * 40];    // K tile [key][40], ch16..31 = 0
    __shared__ __align__(16) float  ps [4][16 * 68]; // per-wave P [q][68]
    __shared__ __align__(16) float  osb[4][16 * 20]; // per-wave epilogue buffer
    __shared__ float asc[4][16], lsc[4][16];

    const int  t     = threadIdx.x;
    const int  lane  = t & 63, w = t >> 6;
    const int  q16   = lane & 15, quad = lane >> 4;
    const int  batch = blockIdx.x >> 6;
    const int  r0    = (blockIdx.x & 63) * 64;
    const long base  = (long)batch * NN;
    const float gm   = gamma[0];

    // zero-fill ks ghost channels 16..31 (read by B-frag quads 2,3) — once
    if (t < 128) {
        int key = t >> 1, hf = t & 1;
        uint4 z = {0u, 0u, 0u, 0u};
        *(uint4*)&ks[key * 40 + 16 + hf * 8] = z;
    }

    // Q A-frag: m = q-row, k = ch (quads 2,3 are the zero padding of k)
    bf16x8 qf;
    #pragma unroll
    for (int j = 0; j < 8; ++j) qf[j] = (__bf16)0.f;
    if (quad < 2)
        qf = *(const bf16x8*)&bqh[(base + r0 + w * 16 + q16) * NCQ + quad * 8];

    float m_[4], l_[4];
    #pragma unroll
    for (int r = 0; r < 4; ++r) { m_[r] = -1e30f; l_[r] = 0.f; }
    f32x4 O[8];
    #pragma unroll
    for (int ct = 0; ct < 8; ++ct) O[ct] = (f32x4){0.f, 0.f, 0.f, 0.f};

    float* psw = ps[w];

    for (int m0 = 0; m0 < NN; m0 += 64) {
        __syncthreads();
        // ---- stage K tile [64][16] -> ks stride 40 ----
        if (t < 128) {
            int key = t >> 1, hf = t & 1;
            *(uint4*)&ks[key * 40 + hf * 8] =
                *(const uint4*)&cqh[(base + m0 + key) * NCQ + hf * 8];
        }
        // ---- stage V^T tile [128][64] -> vt stride 72 ----
        #pragma unroll
        for (int i = 0; i < 4; ++i) {
            int idx = t + 256 * i;       // < 1024
            int ch = idx >> 3, kq = idx & 7;
            *(uint4*)&vt[ch * 72 + kq * 8] =
                *(const uint4*)&dvt[((size_t)batch * 128 + ch) * 4096 + m0 + kq * 8];
        }
        __syncthreads();

        // ---- S = Q*K^T : 4 key-subtiles ----
        f32x4 S[4];
        #pragma unroll
        for (int T = 0; T < 4; ++T) {
            bf16x8 kf = *(const bf16x8*)&ks[(T * 16 + q16) * 40 + quad * 8];
            f32x4 z = {0.f, 0.f, 0.f, 0.f};
            S[T] = MFMA16(qf, kf, z);    // S[q][key]: col=key, row=q
        }

        // ---- online softmax (rows q = quad*4+r, 16 key-lanes per group) ----
        float al[4];
        #pragma unroll
        for (int r = 0; r < 4; ++r) {
            float v = fmaxf(fmaxf(S[0][r], S[1][r]), fmaxf(S[2][r], S[3][r]));
            v = fmaxf(v, __shfl_xor(v, 1));
            v = fmaxf(v, __shfl_xor(v, 2));
            v = fmaxf(v, __shfl_xor(v, 4));
            v = fmaxf(v, __shfl_xor(v, 8));
            float nm = fmaxf(m_[r], v);
            al[r] = __builtin_exp2f((m_[r] - nm) * LOG2E);
            m_[r] = nm;
            float sum = 0.f;
            #pragma unroll
            for (int T = 0; T < 4; ++T) {
                float p = __builtin_exp2f((S[T][r] - nm) * LOG2E);
                psw[(quad * 4 + r) * 68 + T * 16 + q16] = p;
                sum += p;
            }
            sum += __shfl_xor(sum, 1);
            sum += __shfl_xor(sum, 2);
            sum += __shfl_xor(sum, 4);
            sum += __shfl_xor(sum, 8);
            l_[r] = l_[r] * al[r] + sum;
        }
        // broadcast alpha[q] to the lanes that hold O^T column q
        if (q16 == 0) {
            #pragma unroll
            for (int r = 0; r < 4; ++r) asc[w][quad * 4 + r] = al[r];
        }
        float aq = asc[w][q16];
        #pragma unroll
        for (int ct = 0; ct < 8; ++ct) O[ct] *= aq;

        // ---- O^T += V^T * P^T ----
        bf16x8 pf[2];
        #pragma unroll
        for (int kc = 0; kc < 2; ++kc) {
            const float* pr = &psw[q16 * 68 + kc * 32 + quad * 8];
            f32x4 a0 = *(const f32x4*)pr;
            f32x4 a1 = *(const f32x4*)(pr + 4);
            bf16x8 f;
            #pragma unroll
            for (int j = 0; j < 4; ++j) {
                f[j]     = (__bf16)a0[j];
                f[4 + j] = (__bf16)a1[j];
            }
            pf[kc] = f;
        }
        #pragma unroll
        for (int ct = 0; ct < 8; ++ct) {
            #pragma unroll
            for (int kc = 0; kc < 2; ++kc) {
                bf16x8 vf = *(const bf16x8*)&vt[(ct * 16 + q16) * 72 + kc * 32 + quad * 8];
                O[ct] = MFMA16(vf, pf[kc], O[ct]);   // O^T[ch][q]
            }
        }
    }

    // ---- epilogue: out = gamma*(O/l) + x, transposed through LDS ----
    if (q16 == 0) {
        #pragma unroll
        for (int r = 0; r < 4; ++r) lsc[w][quad * 4 + r] = l_[r];
    }
    float gil = gm / lsc[w][q16];
    float* osw = osb[w];
    const int qr = lane >> 2, c4 = (lane & 3) * 4;
    #pragma unroll
    for (int ct = 0; ct < 8; ++ct) {
        #pragma unroll
        for (int r = 0; r < 4; ++r)
            osw[q16 * 20 + quad * 4 + r] = O[ct][r] * gil;   // osb[q][ch16]
        f32x4 v = *(const f32x4*)&osw[qr * 20 + c4];
        size_t g = (size_t)(base + r0 + w * 16 + qr) * NC + ct * 16 + c4;
        f32x4 xv = *(const f32x4*)&x[g];
        v += xv;
        *(f32x4*)&out[g] = v;
    }
}

// ---------------------------------------------------------------------------
extern "C" void kernel_launch(void* const* d_in, const int* in_sizes, int n_in,
                              void* d_out, int out_size, void* d_ws, size_t ws_size,
                              hipStream_t stream) {
    const float* x     = (const float*)d_in[0];
    const float* Wb    = (const float*)d_in[1];
    const float* Wc    = (const float*)d_in[2];
    const float* Wd    = (const float*)d_in[3];
    const float* gamma = (const float*)d_in[4];
    float*       out   = (float*)d_out;

    // ws layout (bf16): bqh [16384*16] | cqh [16384*16] | dvt [4*128*4096]
    __bf16* bqh = (__bf16*)d_ws;
    __bf16* cqh = bqh + (size_t)NROWS * NCQ;
    __bf16* dvt = cqh + (size_t)NROWS * NCQ;

    proj_kernel<<<NROWS / 64, 256, 0, stream>>>(x, Wb, Wc, Wd, bqh, cqh, dvt);
    attn_kernel<<<NB * (NN / 64), 256, 0, stream>>>(bqh, cqh, dvt, x, gamma, out);
}

// Round 3
// 161.229 us; speedup vs baseline: 3.8761x; 1.3557x over previous
//
#include <hip/hip_runtime.h>

// Problem constants: B=4, h=w=z=16 -> N=4096, C=128, Cq=16
#define NB     4
#define NN     4096
#define NC     128
#define NCQ    16
#define NROWS  (NB * NN)      // 16384
#define NSLICE 2
#define KPS    (NN / NSLICE)  // 2048 keys per K-slice
#define NIT    (KPS / 64)     // 32 iterations

typedef __attribute__((ext_vector_type(8)))  __bf16 bf16x8;
typedef __attribute__((ext_vector_type(4)))  float  f32x4;
typedef __attribute__((ext_vector_type(16))) float  f32x16;

#define MFMA16(a,b,c) __builtin_amdgcn_mfma_f32_16x16x32_bf16((a),(b),(c),0,0,0)
#define MFMA32(a,b,c) __builtin_amdgcn_mfma_f32_32x32x16_bf16((a),(b),(c),0,0,0)
#define LOG2E 1.44269504f

__device__ __forceinline__ f32x16 zero16() {
    f32x16 v;
    #pragma unroll
    for (int i = 0; i < 16; ++i) v[i] = 0.f;
    return v;
}

// ---------------------------------------------------------------------------
// Kernel 0: W^T precompute -> wtg[160][128] bf16 (oc: 0..15 Wb, 16..31 Wc,
// 32..159 Wd). Tiny; runs once per launch. Uncoalesced reads but only 80 KB.
// ---------------------------------------------------------------------------
__global__ void wtrans_kernel(const float* __restrict__ Wb,
                              const float* __restrict__ Wc,
                              const float* __restrict__ Wd,
                              __bf16* __restrict__ wtg)
{
    int oc = blockIdx.x;      // 0..159
    int ch = threadIdx.x;     // 0..127
    float v;
    if      (oc < 16) v = Wb[ch * 16  + oc];
    else if (oc < 32) v = Wc[ch * 16  + (oc - 16)];
    else              v = Wd[ch * 128 + (oc - 32)];
    wtg[oc * 128 + ch] = (__bf16)v;
}

// ---------------------------------------------------------------------------
// Kernel 1: projections via MFMA (same verified structure as R2, but W^T is
// staged from precomputed wtg with coalesced uint4 loads — 10 per thread).
// Outputs: bqh/cqh [row][16] bf16 row-major, dvt [batch][ch][4096] bf16 (V^T).
// ---------------------------------------------------------------------------
__global__ __launch_bounds__(256) void proj_kernel(
    const float* __restrict__ x, const __bf16* __restrict__ wtg,
    __bf16* __restrict__ bqh, __bf16* __restrict__ cqh, __bf16* __restrict__ dvt)
{
    __shared__ __align__(16) __bf16 xsh[64 * 136];   // [row][136]
    __shared__ __align__(16) __bf16 wt [160 * 136];  // [outcol][136]
    __shared__ __align__(16) float  osb[4][16 * 17]; // per-wave transpose buffer

    const int  t    = threadIdx.x;
    const int  lane = t & 63, w = t >> 6;
    const int  q16  = lane & 15, quad = lane >> 4;
    const long row0 = (long)blockIdx.x * 64;
    const int  batch = (int)(row0 >> 12);
    const int  nloc  = (int)(row0 & 4095);

    // ---- stage X tile (fp32 -> bf16), [64][128] -> xsh stride 136 ----
    #pragma unroll
    for (int i = 0; i < 8; ++i) {
        int idx = t + 256 * i;           // < 2048
        int r = idx >> 5, c4 = (idx & 31) * 4;
        float4 xv = *(const float4*)&x[(row0 + r) * NC + c4];
        union { __bf16 h[4]; uint2 u; } cv;
        cv.h[0] = (__bf16)xv.x; cv.h[1] = (__bf16)xv.y;
        cv.h[2] = (__bf16)xv.z; cv.h[3] = (__bf16)xv.w;
        *(uint2*)&xsh[r * 136 + c4] = cv.u;
    }
    // ---- stage W^T from wtg: coalesced, 2560 uint4 total ----
    #pragma unroll
    for (int i = 0; i < 10; ++i) {
        int idx = t + 256 * i;           // < 2560
        int oc = idx >> 4, seg = idx & 15;
        *(uint4*)&wt[oc * 136 + seg * 8] = ((const uint4*)wtg)[idx];
    }
    __syncthreads();

    // B-frags (X^T): n = x-row = w*16 + q16, k = ch
    bf16x8 xf[4];
    #pragma unroll
    for (int kc = 0; kc < 4; ++kc)
        xf[kc] = *(const bf16x8*)&xsh[(w * 16 + q16) * 136 + kc * 32 + quad * 8];

    float* osw = osb[w];
    for (int oct = 0; oct < 10; ++oct) {
        f32x4 acc = {0.f, 0.f, 0.f, 0.f};
        #pragma unroll
        for (int kc = 0; kc < 4; ++kc) {
            bf16x8 wf = *(const bf16x8*)&wt[(oct * 16 + q16) * 136 + kc * 32 + quad * 8];
            acc = MFMA16(wf, xf[kc], acc);   // D'[oc][row]
        }
        // D' layout: col = x-row = lane&15, row = oc16 = quad*4+reg
        #pragma unroll
        for (int r = 0; r < 4; ++r)
            osw[(quad * 4 + r) * 17 + q16] = acc[r];   // osb[oc16][xrow]

        if (oct >= 2) {   // -> dvt[ch][row], pack 4 consecutive rows
            int ocp = lane >> 2, rseg = (lane & 3) * 4;
            union { __bf16 h[4]; uint2 u; } cv;
            #pragma unroll
            for (int j = 0; j < 4; ++j) cv.h[j] = (__bf16)osw[ocp * 17 + rseg + j];
            int ch = (oct - 2) * 16 + ocp;
            size_t g = ((size_t)batch * NC + ch) * NN + nloc + w * 16 + rseg;
            *(uint2*)&dvt[g] = cv.u;
        } else {          // -> bqh/cqh row-major
            int r = lane >> 2, seg = lane & 3;
            union { __bf16 h[4]; uint2 u; } cv;
            #pragma unroll
            for (int j = 0; j < 4; ++j) cv.h[j] = (__bf16)osw[(seg * 4 + j) * 17 + r];
            __bf16* dst = (oct == 0) ? bqh : cqh;
            size_t g = (size_t)(row0 + w * 16 + r) * NCQ + seg * 4;
            *(uint2*)&dst[g] = cv.u;
        }
    }
}

// ---------------------------------------------------------------------------
// Kernel 2: flash attention, split-K(x2), no-max softmax, 32x32x16 MFMA.
// Grid 512 = 4 batches x 64 Q-tiles x 2 K-slices; 256 threads = 4 waves.
// Wave w: S^T quadrant (key-half kh=w&1, q-half qh=w>>1); PV O[q][ch] pair
// (q-half pq=w&1, ch-group cg=w>>1). K/V fragments read straight from global
// (L1/L2-hot); P double-buffered in LDS -> ONE barrier per iteration.
// Partials: Opart bf16 [slice][row][ch], lws fp32 [slice][row].
// ---------------------------------------------------------------------------
__global__ __launch_bounds__(256) void attn_kernel(
    const __bf16* __restrict__ bqh, const __bf16* __restrict__ cqh,
    const __bf16* __restrict__ dvt, __bf16* __restrict__ Opart,
    float* __restrict__ lws)
{
    __shared__ __align__(16) __bf16 ps[2][64 * 72];  // P [q][key], dbl-buffered
    __shared__ float lpart[64];

    const int  t    = threadIdx.x;
    const int  lane = t & 63, w = t >> 6;
    const int  l31  = lane & 31, lh = lane >> 5;
    const int  bid   = blockIdx.x;
    const int  slice = bid & 1;
    const int  batch = (bid >> 1) >> 6;
    const int  qt    = (bid >> 1) & 63;
    const long base  = (long)batch * NN;
    const int  q0    = qt * 64;
    const int  ks0   = slice * KPS;

    const int kh = w & 1, qh = w >> 1;   // S^T quadrant assignment
    const int pq = w & 1, cg = w >> 1;   // PV assignment

    if (t < 64) lpart[t] = 0.f;

    // Q^T B-frag (fixed all kernel): n = q = q0+32*qh+l31, k = ch = lh*8+j
    const bf16x8 qf = *(const bf16x8*)&bqh[(base + q0 + 32 * qh + l31) * NCQ + lh * 8];

    f32x16 O[2] = { zero16(), zero16() };
    float  l_loc = 0.f;
    const int qi = 32 * qh + l31;        // local q col for S^T

    for (int it = 0; it < NIT; ++it) {
        const int m0 = ks0 + it * 64;
        __bf16* psb = ps[it & 1];

        // K A-frag: m = key = m0+32*kh+l31, k = ch
        bf16x8 kf = *(const bf16x8*)&cqh[(base + m0 + 32 * kh + l31) * NCQ + lh * 8];
        f32x16 S = MFMA32(kf, qf, zero16());   // S^T[key][q]: col=q, row=key

        // no-max softmax: p = exp(S) (clamped), accumulate l, write 4-packs
        #pragma unroll
        for (int g = 0; g < 4; ++g) {
            union { __bf16 h[4]; uint2 u; } pk;
            #pragma unroll
            for (int j = 0; j < 4; ++j) {
                float e = fminf(S[4 * g + j] * LOG2E, 100.f);  // cap at 2^100
                float p = __builtin_exp2f(e);
                l_loc += p;
                pk.h[j] = (__bf16)p;
            }
            int kr = 32 * kh + 8 * g + 4 * lh;   // 4 consecutive keys
            *(uint2*)&psb[qi * 72 + kr] = pk.u;
        }
        __syncthreads();

        // PV: O[q][ch] += P * V  (A = P from LDS, B = V^T rows from global)
        #pragma unroll
        for (int kc = 0; kc < 4; ++kc) {
            bf16x8 pf = *(const bf16x8*)&psb[(32 * pq + l31) * 72 + kc * 16 + lh * 8];
            #pragma unroll
            for (int ct = 0; ct < 2; ++ct) {
                int ch = 64 * cg + 32 * ct + l31;
                bf16x8 vf = *(const bf16x8*)
                    &dvt[((size_t)batch * NC + ch) * NN + m0 + kc * 16 + lh * 8];
                O[ct] = MFMA32(pf, vf, O[ct]);
            }
        }
    }

    // ---- l reduction: lane pair (disjoint keys, same q), then LDS atomic ----
    l_loc += __shfl_xor(l_loc, 32);
    if (lane < 32) atomicAdd(&lpart[32 * qh + l31], l_loc);
    __syncthreads();
    if (t < 64) lws[(size_t)slice * NROWS + base + q0 + t] = lpart[t];

    // ---- O partial -> global bf16 [slice][row][ch] ----
    #pragma unroll
    for (int ct = 0; ct < 2; ++ct) {
        #pragma unroll
        for (int r = 0; r < 16; ++r) {
            int q  = 32 * pq + (r & 3) + 8 * (r >> 2) + 4 * lh;
            int ch = 64 * cg + 32 * ct + l31;
            Opart[((size_t)slice * NROWS + base + q0 + q) * NC + ch] = (__bf16)O[ct][r];
        }
    }
}

// ---------------------------------------------------------------------------
// Kernel 3: combine split-K partials + epilogue: out = gamma*(SumO/Suml) + x.
// ---------------------------------------------------------------------------
__global__ __launch_bounds__(256) void combine_kernel(
    const __bf16* __restrict__ Op, const float* __restrict__ lws,
    const float* __restrict__ x, const float* __restrict__ gamma,
    float* __restrict__ out)
{
    __shared__ float gl[64];
    const int  t    = threadIdx.x;
    const long row0 = (long)blockIdx.x * 64;
    if (t < 64) {
        float l = lws[row0 + t] + lws[(size_t)NROWS + row0 + t];
        gl[t] = gamma[0] / l;
    }
    __syncthreads();
    const size_t s1 = (size_t)NROWS * NC;
    #pragma unroll
    for (int i = 0; i < 8; ++i) {
        int idx = t + 256 * i;                 // < 2048 float4 groups
        int r = idx >> 5, c4 = (idx & 31) * 4;
        size_t g = (size_t)(row0 + r) * NC + c4;
        union { __bf16 h[4]; uint2 u; } a, b;
        a.u = *(const uint2*)&Op[g];
        b.u = *(const uint2*)&Op[s1 + g];
        float s = gl[r];
        float4 xv = *(const float4*)&x[g];
        float4 o;
        o.x = ((float)a.h[0] + (float)b.h[0]) * s + xv.x;
        o.y = ((float)a.h[1] + (float)b.h[1]) * s + xv.y;
        o.z = ((float)a.h[2] + (float)b.h[2]) * s + xv.z;
        o.w = ((float)a.h[3] + (float)b.h[3]) * s + xv.w;
        *(float4*)&out[g] = o;
    }
}

// ---------------------------------------------------------------------------
extern "C" void kernel_launch(void* const* d_in, const int* in_sizes, int n_in,
                              void* d_out, int out_size, void* d_ws, size_t ws_size,
                              hipStream_t stream) {
    const float* x     = (const float*)d_in[0];
    const float* Wb    = (const float*)d_in[1];
    const float* Wc    = (const float*)d_in[2];
    const float* Wd    = (const float*)d_in[3];
    const float* gamma = (const float*)d_in[4];
    float*       out   = (float*)d_out;

    // ws layout: bqh 512K | cqh 512K | dvt 4M | wtg 40K | Opart 8M | lws 128K
    __bf16* bqh   = (__bf16*)d_ws;
    __bf16* cqh   = bqh + (size_t)NROWS * NCQ;
    __bf16* dvt   = cqh + (size_t)NROWS * NCQ;
    __bf16* wtg   = dvt + (size_t)NB * NC * NN;
    __bf16* Opart = wtg + 160 * 128;
    float*  lws   = (float*)(Opart + (size_t)NSLICE * NROWS * NC);

    wtrans_kernel <<<160, 128, 0, stream>>>(Wb, Wc, Wd, wtg);
    proj_kernel   <<<NROWS / 64, 256, 0, stream>>>(x, wtg, bqh, cqh, dvt);
    attn_kernel   <<<NB * 64 * NSLICE, 256, 0, stream>>>(bqh, cqh, dvt, Opart, lws);
    combine_kernel<<<NROWS / 64, 256, 0, stream>>>(Opart, lws, x, gamma, out);
}

// Round 4
// 146.112 us; speedup vs baseline: 4.2771x; 1.1035x over previous
//
#include <hip/hip_runtime.h>

// Problem constants: B=4, h=w=z=16 -> N=4096, C=128, Cq=16
#define NB     4
#define NN     4096
#define NC     128
#define NCQ    16
#define NROWS  (NB * NN)      // 16384

typedef __attribute__((ext_vector_type(8)))  __bf16 bf16x8;
typedef __attribute__((ext_vector_type(4)))  float  f32x4;
typedef __attribute__((ext_vector_type(16))) float  f32x16;

#define MFMA16(a,b,c) __builtin_amdgcn_mfma_f32_16x16x32_bf16((a),(b),(c),0,0,0)
#define MFMA32(a,b,c) __builtin_amdgcn_mfma_f32_32x32x16_bf16((a),(b),(c),0,0,0)
#define LOG2E 1.44269504f

__device__ __forceinline__ f32x16 zero16() {
    f32x16 v;
    #pragma unroll
    for (int i = 0; i < 16; ++i) v[i] = 0.f;
    return v;
}

// ---------------------------------------------------------------------------
// Kernel 0: W^T precompute -> wtg[160][128] bf16 (oc: 0..15 Wb, 16..31 Wc,
// 32..159 Wd). Tiny; runs once per launch.
// ---------------------------------------------------------------------------
__global__ void wtrans_kernel(const float* __restrict__ Wb,
                              const float* __restrict__ Wc,
                              const float* __restrict__ Wd,
                              __bf16* __restrict__ wtg)
{
    int oc = blockIdx.x;      // 0..159
    int ch = threadIdx.x;     // 0..127
    float v;
    if      (oc < 16) v = Wb[ch * 16  + oc];
    else if (oc < 32) v = Wc[ch * 16  + (oc - 16)];
    else              v = Wd[ch * 128 + (oc - 32)];
    wtg[oc * 128 + ch] = (__bf16)v;
}

// ---------------------------------------------------------------------------
// Kernel 1: projections via MFMA (verified R2/R3 structure).
// Outputs: bqh/cqh [row][16] bf16 row-major, dvt [batch][ch][4096] bf16 (V^T).
// ---------------------------------------------------------------------------
__global__ __launch_bounds__(256) void proj_kernel(
    const float* __restrict__ x, const __bf16* __restrict__ wtg,
    __bf16* __restrict__ bqh, __bf16* __restrict__ cqh, __bf16* __restrict__ dvt)
{
    __shared__ __align__(16) __bf16 xsh[64 * 136];   // [row][136]
    __shared__ __align__(16) __bf16 wt [160 * 136];  // [outcol][136]
    __shared__ __align__(16) float  osb[4][16 * 17]; // per-wave transpose buffer

    const int  t    = threadIdx.x;
    const int  lane = t & 63, w = t >> 6;
    const int  q16  = lane & 15, quad = lane >> 4;
    const long row0 = (long)blockIdx.x * 64;
    const int  batch = (int)(row0 >> 12);
    const int  nloc  = (int)(row0 & 4095);

    // ---- stage X tile (fp32 -> bf16), [64][128] -> xsh stride 136 ----
    #pragma unroll
    for (int i = 0; i < 8; ++i) {
        int idx = t + 256 * i;           // < 2048
        int r = idx >> 5, c4 = (idx & 31) * 4;
        float4 xv = *(const float4*)&x[(row0 + r) * NC + c4];
        union { __bf16 h[4]; uint2 u; } cv;
        cv.h[0] = (__bf16)xv.x; cv.h[1] = (__bf16)xv.y;
        cv.h[2] = (__bf16)xv.z; cv.h[3] = (__bf16)xv.w;
        *(uint2*)&xsh[r * 136 + c4] = cv.u;
    }
    // ---- stage W^T from wtg: coalesced, 2560 uint4 total ----
    #pragma unroll
    for (int i = 0; i < 10; ++i) {
        int idx = t + 256 * i;           // < 2560
        int oc = idx >> 4, seg = idx & 15;
        *(uint4*)&wt[oc * 136 + seg * 8] = ((const uint4*)wtg)[idx];
    }
    __syncthreads();

    // B-frags (X^T): n = x-row = w*16 + q16, k = ch
    bf16x8 xf[4];
    #pragma unroll
    for (int kc = 0; kc < 4; ++kc)
        xf[kc] = *(const bf16x8*)&xsh[(w * 16 + q16) * 136 + kc * 32 + quad * 8];

    float* osw = osb[w];
    for (int oct = 0; oct < 10; ++oct) {
        f32x4 acc = {0.f, 0.f, 0.f, 0.f};
        #pragma unroll
        for (int kc = 0; kc < 4; ++kc) {
            bf16x8 wf = *(const bf16x8*)&wt[(oct * 16 + q16) * 136 + kc * 32 + quad * 8];
            acc = MFMA16(wf, xf[kc], acc);   // D'[oc][row]
        }
        // D' layout: col = x-row = lane&15, row = oc16 = quad*4+reg
        #pragma unroll
        for (int r = 0; r < 4; ++r)
            osw[(quad * 4 + r) * 17 + q16] = acc[r];   // osb[oc16][xrow]

        if (oct >= 2) {   // -> dvt[ch][row], pack 4 consecutive rows
            int ocp = lane >> 2, rseg = (lane & 3) * 4;
            union { __bf16 h[4]; uint2 u; } cv;
            #pragma unroll
            for (int j = 0; j < 4; ++j) cv.h[j] = (__bf16)osw[ocp * 17 + rseg + j];
            int ch = (oct - 2) * 16 + ocp;
            size_t g = ((size_t)batch * NC + ch) * NN + nloc + w * 16 + rseg;
            *(uint2*)&dvt[g] = cv.u;
        } else {          // -> bqh/cqh row-major
            int r = lane >> 2, seg = lane & 3;
            union { __bf16 h[4]; uint2 u; } cv;
            #pragma unroll
            for (int j = 0; j < 4; ++j) cv.h[j] = (__bf16)osw[(seg * 4 + j) * 17 + r];
            __bf16* dst = (oct == 0) ? bqh : cqh;
            size_t g = (size_t)(row0 + w * 16 + r) * NCQ + seg * 4;
            *(uint2*)&dst[g] = cv.u;
        }
    }
}

// ---------------------------------------------------------------------------
// Kernel 2: flash attention, split-K (runtime 2 or 4), no-max softmax,
// 32x32x16 MFMA, software-pipelined: next-iter K prefetched right after the
// S-MFMA, current-iter V fragments issued before the exp phase so their
// global latency hides behind exp + barrier. One barrier/iter (P dbl-buffer).
// ---------------------------------------------------------------------------
template<int NIT_T>
__global__ __launch_bounds__(256, 4) void attn_kernel(
    const __bf16* __restrict__ bqh, const __bf16* __restrict__ cqh,
    const __bf16* __restrict__ dvt, __bf16* __restrict__ Opart,
    float* __restrict__ lws, int smask, int sshift)
{
    __shared__ __align__(16) __bf16 ps[2][64 * 72];  // P [q][key], dbl-buffered
    __shared__ float lpart[64];

    const int  t    = threadIdx.x;
    const int  lane = t & 63, w = t >> 6;
    const int  l31  = lane & 31, lh = lane >> 5;
    const int  bid   = blockIdx.x;
    const int  slice = bid & smask;
    const int  qb    = bid >> sshift;
    const int  batch = qb >> 6;
    const int  qt    = qb & 63;
    const long base  = (long)batch * NN;
    const int  q0    = qt * 64;
    const int  ks0   = slice * (64 * NIT_T);

    const int kh = w & 1, qh = w >> 1;   // S^T quadrant assignment
    const int pq = w & 1, cg = w >> 1;   // PV assignment

    if (t < 64) lpart[t] = 0.f;

    // Q^T B-frag (fixed): n = q = q0+32*qh+l31, k = ch = lh*8+j
    const bf16x8 qf = *(const bf16x8*)&bqh[(base + q0 + 32 * qh + l31) * NCQ + lh * 8];

    const __bf16* kptr  = &cqh[(base + ks0 + 32 * kh + l31) * NCQ + lh * 8];
    const __bf16* vbase = &dvt[(size_t)batch * NC * NN + ks0 + lh * 8];

    f32x16 O[2] = { zero16(), zero16() };
    float  l_loc = 0.f;
    const int qi = 32 * qh + l31;

    bf16x8 kf = *(const bf16x8*)kptr;    // iter 0 K-frag

    #pragma unroll 2
    for (int it = 0; it < NIT_T; ++it) {
        __bf16* psb = ps[it & 1];

        f32x16 S = MFMA32(kf, qf, zero16());   // S^T[key][q]

        // prefetch next K-frag (clamped; uniform branch-free)
        int itn = (it + 1 < NIT_T) ? it + 1 : it;
        kf = *(const bf16x8*)(kptr + (size_t)itn * 64 * NCQ);

        // current-iter V frags: no LDS dependency -> issue before exp phase
        bf16x8 vf[8];
        #pragma unroll
        for (int ct = 0; ct < 2; ++ct)
            #pragma unroll
            for (int kc = 0; kc < 4; ++kc)
                vf[ct * 4 + kc] = *(const bf16x8*)
                    &vbase[(size_t)(64 * cg + 32 * ct + l31) * NN + it * 64 + kc * 16];

        // no-max softmax: p = exp(S) (clamped), accumulate l, write 4-packs
        #pragma unroll
        for (int g = 0; g < 4; ++g) {
            union { __bf16 h[4]; uint2 u; } pk;
            #pragma unroll
            for (int j = 0; j < 4; ++j) {
                float e = fminf(S[4 * g + j] * LOG2E, 100.f);
                float p = __builtin_exp2f(e);
                l_loc += p;
                pk.h[j] = (__bf16)p;
            }
            int kr = 32 * kh + 8 * g + 4 * lh;
            *(uint2*)&psb[qi * 72 + kr] = pk.u;
        }
        __syncthreads();

        // PV: O[q][ch] += P * V
        #pragma unroll
        for (int kc = 0; kc < 4; ++kc) {
            bf16x8 pf = *(const bf16x8*)&psb[(32 * pq + l31) * 72 + kc * 16 + lh * 8];
            O[0] = MFMA32(pf, vf[kc],     O[0]);
            O[1] = MFMA32(pf, vf[4 + kc], O[1]);
        }
    }

    // ---- l reduction: lane pair (disjoint keys, same q), then LDS atomic ----
    l_loc += __shfl_xor(l_loc, 32);
    if (lane < 32) atomicAdd(&lpart[32 * qh + l31], l_loc);
    __syncthreads();
    if (t < 64) lws[(size_t)slice * NROWS + base + q0 + t] = lpart[t];

    // ---- O partial -> global bf16 [slice][row][ch] ----
    #pragma unroll
    for (int ct = 0; ct < 2; ++ct) {
        #pragma unroll
        for (int r = 0; r < 16; ++r) {
            int q  = 32 * pq + (r & 3) + 8 * (r >> 2) + 4 * lh;
            int ch = 64 * cg + 32 * ct + l31;
            Opart[((size_t)slice * NROWS + base + q0 + q) * NC + ch] = (__bf16)O[ct][r];
        }
    }
}

// ---------------------------------------------------------------------------
// Kernel 3: combine split-K partials + epilogue: out = gamma*(SumO/Suml) + x.
// 512 blocks x 32 rows.
// ---------------------------------------------------------------------------
__global__ __launch_bounds__(256) void combine_kernel(
    const __bf16* __restrict__ Op, const float* __restrict__ lws,
    const float* __restrict__ x, const float* __restrict__ gamma,
    float* __restrict__ out, int nslice)
{
    __shared__ float gl[32];
    const int  t    = threadIdx.x;
    const long row0 = (long)blockIdx.x * 32;
    if (t < 32) {
        float l = 0.f;
        for (int s = 0; s < nslice; ++s) l += lws[(size_t)s * NROWS + row0 + t];
        gl[t] = gamma[0] / l;
    }
    __syncthreads();
    const size_t s1 = (size_t)NROWS * NC;
    #pragma unroll
    for (int i = 0; i < 4; ++i) {
        int idx = t + 256 * i;                 // < 1024 float4 groups
        int r = idx >> 5, c4 = (idx & 31) * 4;
        size_t g = (size_t)(row0 + r) * NC + c4;
        float a0 = 0.f, a1 = 0.f, a2 = 0.f, a3 = 0.f;
        for (int s = 0; s < nslice; ++s) {
            union { __bf16 h[4]; uint2 u; } a;
            a.u = *(const uint2*)&Op[s1 * s + g];
            a0 += (float)a.h[0]; a1 += (float)a.h[1];
            a2 += (float)a.h[2]; a3 += (float)a.h[3];
        }
        float sc = gl[r];
        float4 xv = *(const float4*)&x[g];
        float4 o;
        o.x = a0 * sc + xv.x; o.y = a1 * sc + xv.y;
        o.z = a2 * sc + xv.z; o.w = a3 * sc + xv.w;
        *(float4*)&out[g] = o;
    }
}

// ---------------------------------------------------------------------------
extern "C" void kernel_launch(void* const* d_in, const int* in_sizes, int n_in,
                              void* d_out, int out_size, void* d_ws, size_t ws_size,
                              hipStream_t stream) {
    const float* x     = (const float*)d_in[0];
    const float* Wb    = (const float*)d_in[1];
    const float* Wc    = (const float*)d_in[2];
    const float* Wd    = (const float*)d_in[3];
    const float* gamma = (const float*)d_in[4];
    float*       out   = (float*)d_out;

    // ws layout: bqh 512K | cqh 512K | dvt 4M | wtg 40K | Opart nslice*4M | lws
    const size_t fixed = (size_t)NROWS * NCQ * 2 * 2 /*bqh+cqh bytes*/
                       + (size_t)NB * NC * NN * 2    /*dvt*/
                       + 160 * 128 * 2;              /*wtg*/
    const size_t need4 = fixed + 4ull * NROWS * NC * 2 + 4ull * NROWS * 4;
    const int nslice = (ws_size >= need4) ? 4 : 2;

    __bf16* bqh   = (__bf16*)d_ws;
    __bf16* cqh   = bqh + (size_t)NROWS * NCQ;
    __bf16* dvt   = cqh + (size_t)NROWS * NCQ;
    __bf16* wtg   = dvt + (size_t)NB * NC * NN;
    __bf16* Opart = wtg + 160 * 128;
    float*  lws   = (float*)(Opart + (size_t)nslice * NROWS * NC);

    wtrans_kernel <<<160, 128, 0, stream>>>(Wb, Wc, Wd, wtg);
    proj_kernel   <<<NROWS / 64, 256, 0, stream>>>(x, wtg, bqh, cqh, dvt);
    if (nslice == 4)
        attn_kernel<16><<<NB * 64 * 4, 256, 0, stream>>>(bqh, cqh, dvt, Opart, lws, 3, 2);
    else
        attn_kernel<32><<<NB * 64 * 2, 256, 0, stream>>>(bqh, cqh, dvt, Opart, lws, 1, 1);
    combine_kernel<<<NROWS / 32, 256, 0, stream>>>(Opart, lws, x, gamma, out, nslice);
}

// Round 5
// 145.831 us; speedup vs baseline: 4.2854x; 1.0019x over previous
//
#include <hip/hip_runtime.h>

// Problem constants: B=4, h=w=z=16 -> N=4096, C=128, Cq=16
#define NB     4
#define NN     4096
#define NC     128
#define NCQ    16
#define NROWS  (NB * NN)      // 16384

typedef __attribute__((ext_vector_type(8)))  __bf16 bf16x8;
typedef __attribute__((ext_vector_type(4)))  float  f32x4;
typedef __attribute__((ext_vector_type(16))) float  f32x16;

#define MFMA16(a,b,c) __builtin_amdgcn_mfma_f32_16x16x32_bf16((a),(b),(c),0,0,0)
#define MFMA32(a,b,c) __builtin_amdgcn_mfma_f32_32x32x16_bf16((a),(b),(c),0,0,0)
#define LOG2E 1.44269504f

__device__ __forceinline__ f32x16 zero16() {
    f32x16 v;
    #pragma unroll
    for (int i = 0; i < 16; ++i) v[i] = 0.f;
    return v;
}

// Swizzled fragment layouts (lane = lh*32 + l31):
//  qswz: [batch][qb32][lane][8]  elem j = Q[32*qb32 + l31][ch = 8*lh + j]
//  kswz: [batch][kb32][lane][8]  elem j = K[32*kb32 + l31][ch = 8*lh + j]
//  vswz: [batch][kb16][cg][lane][8]
//        elem j = V^T[ch = 32*cg + l31][key = 16*kb16 + 4*lh + (j&3) + 8*(j>>2)]
//  (key order matches the S^T C-layout reg order — MFMA contracts by slot,
//   so P needs no cross-lane exchange at all.)

// ---------------------------------------------------------------------------
// Kernel 0: W^T precompute -> wtg[160][128] bf16 (oc: 0..15 Wb, 16..31 Wc,
// 32..159 Wd).
// ---------------------------------------------------------------------------
__global__ void wtrans_kernel(const float* __restrict__ Wb,
                              const float* __restrict__ Wc,
                              const float* __restrict__ Wd,
                              __bf16* __restrict__ wtg)
{
    int oc = blockIdx.x;      // 0..159
    int ch = threadIdx.x;     // 0..127
    float v;
    if      (oc < 16) v = Wb[ch * 16  + oc];
    else if (oc < 32) v = Wc[ch * 16  + (oc - 16)];
    else              v = Wd[ch * 128 + (oc - 32)];
    wtg[oc * 128 + ch] = (__bf16)v;
}

// ---------------------------------------------------------------------------
// Kernel 1: projections via MFMA. 32 rows/block, grid 512 (2 blocks/CU).
// Wave w: row-half rh=w&1 (16 rows), oset group og=(w>>1)*5 (5 of 10 outputs).
// oset 0 -> qswz, 1 -> kswz, 2..9 -> vswz (16 ch each).
// ---------------------------------------------------------------------------
__global__ __launch_bounds__(256) void proj_kernel(
    const float* __restrict__ x, const __bf16* __restrict__ wtg,
    __bf16* __restrict__ qswz, __bf16* __restrict__ kswz, __bf16* __restrict__ vswz)
{
    __shared__ __align__(16) __bf16 xsh[32 * 136];   // [row][136]
    __shared__ __align__(16) __bf16 wt [160 * 136];  // [outcol][136]
    __shared__ __align__(16) float  osb[4][16 * 17]; // per-wave transpose buffer

    const int  t    = threadIdx.x;
    const int  lane = t & 63, w = t >> 6;
    const int  q16  = lane & 15, quad = lane >> 4;
    const long row0 = (long)blockIdx.x * 32;
    const int  batch = (int)(row0 >> 12);
    const int  nloc  = (int)(row0 & 4095);
    const int  rh   = w & 1;
    const int  og   = (w >> 1) * 5;

    // ---- stage X tile (fp32 -> bf16), [32][128] -> xsh stride 136 ----
    #pragma unroll
    for (int i = 0; i < 4; ++i) {
        int idx = t + 256 * i;           // < 1024
        int r = idx >> 5, c4 = (idx & 31) * 4;
        float4 xv = *(const float4*)&x[(row0 + r) * NC + c4];
        union { __bf16 h[4]; uint2 u; } cv;
        cv.h[0] = (__bf16)xv.x; cv.h[1] = (__bf16)xv.y;
        cv.h[2] = (__bf16)xv.z; cv.h[3] = (__bf16)xv.w;
        *(uint2*)&xsh[r * 136 + c4] = cv.u;
    }
    // ---- stage W^T from wtg: coalesced, 2560 uint4 ----
    #pragma unroll
    for (int i = 0; i < 10; ++i) {
        int idx = t + 256 * i;           // < 2560
        int oc = idx >> 4, seg = idx & 15;
        *(uint4*)&wt[oc * 136 + seg * 8] = ((const uint4*)wtg)[idx];
    }
    __syncthreads();

    // B-frags (X^T): n = x-row = rh*16 + q16, k = ch
    bf16x8 xf[4];
    #pragma unroll
    for (int kc = 0; kc < 4; ++kc)
        xf[kc] = *(const bf16x8*)&xsh[(rh * 16 + q16) * 136 + kc * 32 + quad * 8];

    float* osw = osb[w];
    #pragma unroll
    for (int oc_t = 0; oc_t < 5; ++oc_t) {
        const int oset = og + oc_t;
        f32x4 acc = {0.f, 0.f, 0.f, 0.f};
        #pragma unroll
        for (int kc = 0; kc < 4; ++kc) {
            bf16x8 wf = *(const bf16x8*)&wt[(oset * 16 + q16) * 136 + kc * 32 + quad * 8];
            acc = MFMA16(wf, xf[kc], acc);   // D'[oc][row]
        }
        // D' layout: col = x-row16 = lane&15, row = oc16 = quad*4+reg
        #pragma unroll
        for (int r = 0; r < 4; ++r)
            osw[(quad * 4 + r) * 17 + q16] = acc[r];   // osb[oc16][xrow16]

        if (oset >= 2) {
            // -> vswz: lane: ch_l = l&15, lh_t = (l>>4)&1, jh = l>>5
            int ch_l = lane & 15, lh_t = (lane >> 4) & 1, jh = lane >> 5;
            union { __bf16 h[4]; uint2 u; } cv;
            #pragma unroll
            for (int u2 = 0; u2 < 4; ++u2)
                cv.h[u2] = (__bf16)osw[ch_l * 17 + 8 * jh + 4 * lh_t + u2];
            int kb16 = (nloc >> 4) + rh;
            int cg   = (oset - 2) >> 1;
            int l31v = ((oset - 2) & 1) * 16 + ch_l;
            size_t off = ((((size_t)batch * 256 + kb16) * 4 + cg) << 9)
                       + (size_t)(lh_t * 32 + l31v) * 8 + jh * 4;
            *(uint2*)&vswz[off] = cv.u;
        } else if (lane < 32) {
            // -> qswz/kswz: lane: xr = l&15, lh_t = l>>4; 8 ch per uint4
            int xr = lane & 15, lh_t = lane >> 4;
            union { __bf16 h[8]; uint4 u; } cv;
            #pragma unroll
            for (int j = 0; j < 8; ++j)
                cv.h[j] = (__bf16)osw[(8 * lh_t + j) * 17 + xr];
            size_t off = ((((size_t)batch * 128 + (nloc >> 5)) * 64)
                       + (size_t)(lh_t * 32 + rh * 16 + xr)) * 8;
            __bf16* dst = (oset == 0) ? qswz : kswz;
            *(uint4*)&dst[off] = cv.u;
        }
    }
}

// ---------------------------------------------------------------------------
// Kernel 2: flash attention — barrier-free, LDS-free, one wave per 32 q rows.
// Grid = 4 batches x 128 qb32 x nslice, block = 64 threads (1 wave).
// Per 64-key iter: 2 S^T MFMAs, 32 exps, pack-in-place -> P A-frags
// (slot order matches vswz key order), 16 PV MFMAs with coalesced V frags.
// ---------------------------------------------------------------------------
template<int NIT_T>
__global__ __launch_bounds__(64, 2) void attn_kernel(
    const __bf16* __restrict__ qswz, const __bf16* __restrict__ kswz,
    const __bf16* __restrict__ vswz, __bf16* __restrict__ Opart,
    float* __restrict__ lws, int smask, int sshift)
{
    const int lane = threadIdx.x;
    const int l31 = lane & 31, lh = lane >> 5;
    const int bid   = blockIdx.x;
    const int slice = bid & smask;
    const int u     = bid >> sshift;
    const int batch = u >> 7;
    const int qb32  = u & 127;
    const int ks0   = slice * (64 * NIT_T);

    // Q B-frag, fixed: n = q = 32*qb32 + l31, k = ch = 8*lh + j
    const bf16x8 qf = *(const bf16x8*)
        &qswz[(((size_t)batch * 128 + qb32) * 64 + lane) * 8];

    const __bf16* kbase = kswz + ((size_t)batch * 128 + (ks0 >> 5)) * 512 + lane * 8;
    const __bf16* vbase = vswz + ((size_t)batch * 256 + (ks0 >> 4)) * 2048 + lane * 8;

    f32x16 O0 = zero16(), O1 = zero16(), O2 = zero16(), O3 = zero16();
    float l_loc = 0.f;

    bf16x8 kf0 = *(const bf16x8*)(kbase);
    bf16x8 kf1 = *(const bf16x8*)(kbase + 512);

    for (int it = 0; it < NIT_T; ++it) {
        // S^T = K·Q^T : col = q = l31, reg r = key (r&3)+8*(r>>2)+4*lh
        f32x16 S0 = MFMA32(kf0, qf, zero16());
        f32x16 S1 = MFMA32(kf1, qf, zero16());

        // current-iter V fragments: 16 coalesced dwordx4 loads
        bf16x8 vf[16];
        #pragma unroll
        for (int b = 0; b < 4; ++b)
            #pragma unroll
            for (int cg = 0; cg < 4; ++cg)
                vf[b * 4 + cg] = *(const bf16x8*)
                    (vbase + ((size_t)(it * 4 + b) * 4 + cg) * 512);

        // next-iter K fragments (clamped)
        int itn = (it + 1 < NIT_T) ? it + 1 : it;
        kf0 = *(const bf16x8*)(kbase + (size_t)itn * 1024);
        kf1 = *(const bf16x8*)(kbase + (size_t)itn * 1024 + 512);

        // exp + pack in reg order => pk.f[b] is the PV A-frag for key-block b
        union { uint32_t u32[16]; bf16x8 f[4]; } pk;
        #pragma unroll
        for (int i = 0; i < 8; ++i) {
            float p0 = __builtin_exp2f(fminf(S0[2*i]   * LOG2E, 100.f));
            float p1 = __builtin_exp2f(fminf(S0[2*i+1] * LOG2E, 100.f));
            float p2 = __builtin_exp2f(fminf(S1[2*i]   * LOG2E, 100.f));
            float p3 = __builtin_exp2f(fminf(S1[2*i+1] * LOG2E, 100.f));
            l_loc += p0 + p1 + p2 + p3;
            union { __bf16 h[2]; uint32_t v; } a, b2;
            a.h[0]  = (__bf16)p0; a.h[1]  = (__bf16)p1;
            b2.h[0] = (__bf16)p2; b2.h[1] = (__bf16)p3;
            pk.u32[i] = a.v; pk.u32[8 + i] = b2.v;
        }

        // PV: O[q][ch] += P·V (A = P slots, B = vswz, same key order per slot)
        #pragma unroll
        for (int b = 0; b < 4; ++b) {
            O0 = MFMA32(pk.f[b], vf[b * 4 + 0], O0);
            O1 = MFMA32(pk.f[b], vf[b * 4 + 1], O1);
            O2 = MFMA32(pk.f[b], vf[b * 4 + 2], O2);
            O3 = MFMA32(pk.f[b], vf[b * 4 + 3], O3);
        }
    }

    // ---- l: lane-pair sum (disjoint key halves, same q) ----
    float l_tot = l_loc + __shfl_xor(l_loc, 32);
    const long base = (long)batch * NN;
    if (lane < 32)
        lws[(size_t)slice * NROWS + base + qb32 * 32 + lane] = l_tot;

    // ---- O partial -> Opart[slice][row][ch] (C-layout: col=ch=l31) ----
    #pragma unroll
    for (int cg = 0; cg < 4; ++cg) {
        f32x16 Ov = (cg == 0) ? O0 : (cg == 1) ? O1 : (cg == 2) ? O2 : O3;
        #pragma unroll
        for (int r = 0; r < 16; ++r) {
            int q = qb32 * 32 + (r & 3) + 8 * (r >> 2) + 4 * lh;
            Opart[((size_t)slice * NROWS + base + q) * NC + cg * 32 + l31] = (__bf16)Ov[r];
        }
    }
}

// ---------------------------------------------------------------------------
// Kernel 3: combine split-K partials + epilogue: out = gamma*(SumO/Suml) + x.
// ---------------------------------------------------------------------------
__global__ __launch_bounds__(256) void combine_kernel(
    const __bf16* __restrict__ Op, const float* __restrict__ lws,
    const float* __restrict__ x, const float* __restrict__ gamma,
    float* __restrict__ out, int nslice)
{
    __shared__ float gl[32];
    const int  t    = threadIdx.x;
    const long row0 = (long)blockIdx.x * 32;
    if (t < 32) {
        float l = 0.f;
        for (int s = 0; s < nslice; ++s) l += lws[(size_t)s * NROWS + row0 + t];
        gl[t] = gamma[0] / l;
    }
    __syncthreads();
    const size_t s1 = (size_t)NROWS * NC;
    #pragma unroll
    for (int i = 0; i < 4; ++i) {
        int idx = t + 256 * i;                 // < 1024 float4 groups
        int r = idx >> 5, c4 = (idx & 31) * 4;
        size_t g = (size_t)(row0 + r) * NC + c4;
        float a0 = 0.f, a1 = 0.f, a2 = 0.f, a3 = 0.f;
        for (int s = 0; s < nslice; ++s) {
            union { __bf16 h[4]; uint2 u; } a;
            a.u = *(const uint2*)&Op[s1 * s + g];
            a0 += (float)a.h[0]; a1 += (float)a.h[1];
            a2 += (float)a.h[2]; a3 += (float)a.h[3];
        }
        float sc = gl[r];
        float4 xv = *(const float4*)&x[g];
        float4 o;
        o.x = a0 * sc + xv.x; o.y = a1 * sc + xv.y;
        o.z = a2 * sc + xv.z; o.w = a3 * sc + xv.w;
        *(float4*)&out[g] = o;
    }
}

// ---------------------------------------------------------------------------
extern "C" void kernel_launch(void* const* d_in, const int* in_sizes, int n_in,
                              void* d_out, int out_size, void* d_ws, size_t ws_size,
                              hipStream_t stream) {
    const float* x     = (const float*)d_in[0];
    const float* Wb    = (const float*)d_in[1];
    const float* Wc    = (const float*)d_in[2];
    const float* Wd    = (const float*)d_in[3];
    const float* gamma = (const float*)d_in[4];
    float*       out   = (float*)d_out;

    // ws layout: qswz 512K | kswz 512K | vswz 4M | wtg 40K | Opart nslice*4M | lws
    const size_t fixed = (size_t)NROWS * NCQ * 2 * 2
                       + (size_t)NB * NC * NN * 2
                       + 160 * 128 * 2;
    const size_t need4 = fixed + 4ull * NROWS * NC * 2 + 4ull * NROWS * 4;
    const int nslice = (ws_size >= need4) ? 4 : 2;

    __bf16* qswz  = (__bf16*)d_ws;
    __bf16* kswz  = qswz + (size_t)NROWS * NCQ;
    __bf16* vswz  = kswz + (size_t)NROWS * NCQ;
    __bf16* wtg   = vswz + (size_t)NB * NC * NN;
    __bf16* Opart = wtg + 160 * 128;
    float*  lws   = (float*)(Opart + (size_t)nslice * NROWS * NC);

    wtrans_kernel <<<160, 128, 0, stream>>>(Wb, Wc, Wd, wtg);
    proj_kernel   <<<NROWS / 32, 256, 0, stream>>>(x, wtg, qswz, kswz, vswz);
    if (nslice == 4)
        attn_kernel<16><<<NB * 128 * 4, 64, 0, stream>>>(qswz, kswz, vswz, Opart, lws, 3, 2);
    else
        attn_kernel<32><<<NB * 128 * 2, 64, 0, stream>>>(qswz, kswz, vswz, Opart, lws, 1, 1);
    combine_kernel<<<NROWS / 32, 256, 0, stream>>>(Opart, lws, x, gamma, out, nslice);
}